// Round 6
// baseline (63.974 us; speedup 1.0000x reference)
//
#include <hip/hip_runtime.h>
#include <hip/hip_bf16.h>

// Conv2dLocal: B=64, C_IN=64, H=W=32, C_OUT=64, 3x3, pad 1, stride 1.
// out[b,o,h,w] = sum_{c,kh,kw} x[b,c,h+kh-1,w+kw-1] * wgt[h,w,o,c,kh,kw] + bias[o,h,w]
//
// xpose_k: x[b][c][y][xw] f32 -> xc[y][xw][b][c] bf16 (8 MB in d_ws)
// conv_k:  block = (hw, batch-half). im2col patch [32][640] bf16 in LDS
//   (XOR-swizzled 16B units, conflict-free ds_write_b128 staging). Weights are
//   PER-WAVE PRIVATE: streamed global->VGPR with pinned inline-asm
//   global_load_dwordx4 (depth-8 ring, 16 loads in flight). EARLY-CLOBBER
//   "=&v" outputs are REQUIRED: async loads write their dest registers long
//   after issue, so dest must not overlap the address pair or later reuse.
//   Consumption is fenced by s_waitcnt vmcnt(N) + sched_barrier(0) (rule #18).
//   NO barriers in the K-loop. 4 waves x (32M x 16N) mfma_f32_16x16x32_bf16.

typedef __attribute__((ext_vector_type(8))) short short8;
typedef __attribute__((ext_vector_type(4))) float f32x4;

#define PSTR 640  // patch row stride (bf16 elems) = 80 16B-units; rows 16B-aligned

__device__ __forceinline__ void waitlgkm0() {
  asm volatile("s_waitcnt lgkmcnt(0)" ::: "memory");
}

// Wait until <=N vmem ops outstanding; sched_barrier(0) keeps register-only
// consumers (pack/MFMA) from being hoisted above the wait (guide rule #18).
template <int N>
__device__ __forceinline__ void waitvm() {
  asm volatile("s_waitcnt vmcnt(%0)" ::"i"(N) : "memory");
  __builtin_amdgcn_sched_barrier(0);
}

__global__ __launch_bounds__(256) void xpose_k(const float* __restrict__ x,
                                               unsigned short* __restrict__ xc) {
  __shared__ float tile[64][65];
  int bid = blockIdx.x;  // 64 row-tiles x 16 col-tiles over A[4096][1024]
  int rt = bid >> 4, ct = bid & 15;
  int r0 = rt << 6, c0 = ct << 6;
  int lane = threadIdx.x & 63, wv = threadIdx.x >> 6;
#pragma unroll
  for (int i = 0; i < 16; ++i) {
    int r = (i << 2) + wv;
    tile[r][lane] = x[(size_t)(r0 + r) * 1024 + c0 + lane];
  }
  __syncthreads();
#pragma unroll
  for (int i = 0; i < 16; ++i) {
    int oc = (i << 2) + wv;
    unsigned int u = __float_as_uint(tile[lane][oc]);
    unsigned int r = (u + 0x7FFFu + ((u >> 16) & 1u)) >> 16;  // RNE to bf16
    xc[(size_t)(c0 + oc) * 4096 + r0 + lane] = (unsigned short)r;
  }
}

__global__ __launch_bounds__(256, 3) void conv_k(const unsigned short* __restrict__ xc,
                                                 const float* __restrict__ wgt,
                                                 const float* __restrict__ bias,
                                                 float* __restrict__ out) {
  __shared__ unsigned short patch[32 * PSTR];  // 40,960 B

  int bid = blockIdx.x;
  int xcd = bid & 7, idx = bid >> 3;
  int hw = (xcd << 7) | (idx >> 1);  // XCD gets contiguous hw; both mh same XCD
  int mh = idx & 1;
  int h = hw >> 5, w = hw & 31;
  int t = threadIdx.x;

  // ---- stage im2col half-patch: patch[brow][k], k = c*9+tap, XOR-swizzled units
  {
    int c8 = t & 7;     // c octet
    int brow = t >> 3;  // 0..31
    int b_glob = (mh << 5) + brow;
    uint4 v[9];
#pragma unroll
    for (int tap = 0; tap < 9; ++tap) {
      int y = h + tap / 3 - 1;
      int xw = w + tap % 3 - 1;
      bool valid = ((unsigned)y < 32u) && ((unsigned)xw < 32u);
      uint4 val = make_uint4(0u, 0u, 0u, 0u);
      if (valid)
        val = *(const uint4*)(xc + ((size_t)(y * 32 + xw) << 12) + b_glob * 64 + c8 * 8);
      v[tap] = val;
    }
    unsigned short* dst = patch + brow * PSTR;
    int r7b = brow & 7;
    const unsigned int* vw = (const unsigned int*)v;
#pragma unroll
    for (int u = 0; u < 9; ++u) {
      unsigned int wd[4];
#pragma unroll
      for (int wi = 0; wi < 4; ++wi) {
        const int kl0 = 8 * u + 2 * wi, kl1 = kl0 + 1;
        const int tapA = kl0 % 9, jA = kl0 / 9;
        const int tapB = kl1 % 9, jB = kl1 / 9;
        const unsigned int selLo = (jA & 1) ? 0x0302u : 0x0100u;
        const unsigned int selHi = (jB & 1) ? 0x0706u : 0x0504u;
        wd[wi] = __builtin_amdgcn_perm(vw[tapB * 4 + (jB >> 1)],
                                       vw[tapA * 4 + (jA >> 1)],
                                       selLo | (selHi << 16));
      }
      int u_abs = 9 * c8 + u;
      int u_swz = (u_abs & ~7) | ((u_abs & 7) ^ r7b);
      *(uint4*)(dst + (u_swz << 3)) = make_uint4(wd[0], wd[1], wd[2], wd[3]);
    }
  }

  // ---- per-wave private weight stream: pinned asm loads, depth-8 ring ----
  int wc = t >> 6, lane = t & 63;
  int l15 = lane & 15, l4 = lane >> 4;
  const float* wb = wgt + (size_t)hw * 36864;                 // [64 o][576 k] f32
  const float* wp = wb + (size_t)(wc * 16 + l15) * 576 + l4 * 8;

  float4 pf[8][2];  // all indices static after unroll -> registers

  // EARLY-CLOBBER outputs: async dest regs must not alias the address pair.
#define ISSUE(slot, step)                                              \
  do {                                                                 \
    const float* _a = wp + (step) * 32;                                \
    asm volatile("global_load_dwordx4 %0, %2, off\n\t"                 \
                 "global_load_dwordx4 %1, %2, off offset:16"           \
                 : "=&v"(pf[slot][0]), "=&v"(pf[slot][1])              \
                 : "v"(_a)                                             \
                 : "memory");                                          \
  } while (0)

  // prologue: fill all 8 slots (staging xc loads are fully drained here —
  // their data was consumed by the ds_writes above)
  ISSUE(0, 0); ISSUE(1, 1); ISSUE(2, 2); ISSUE(3, 3);
  ISSUE(4, 4); ISSUE(5, 5); ISSUE(6, 6); ISSUE(7, 7);

  waitlgkm0();                          // own patch ds_writes complete
  __builtin_amdgcn_sched_barrier(0);
  __builtin_amdgcn_s_barrier();         // patch visible; 16 weight loads in flight

  // A-read bases (swizzled): step s unit low3 = (4*(s&1)+l4)^(l15&7)
  int l7 = l15 & 7;
  const unsigned short* apE = patch + l15 * PSTR + ((l4 ^ l7) << 3);
  const unsigned short* apO = patch + l15 * PSTR + (((4 + l4) ^ l7) << 3);

  f32x4 acc0 = {0.f, 0.f, 0.f, 0.f};
  f32x4 acc1 = acc0;

  union S8U { short8 s; unsigned int u[4]; };
  auto pack = [](const float4& lo, const float4& hi) -> short8 {
    S8U r;  // truncate f32->bf16 via v_perm
    r.u[0] = __builtin_amdgcn_perm(__float_as_uint(lo.y), __float_as_uint(lo.x), 0x07060302u);
    r.u[1] = __builtin_amdgcn_perm(__float_as_uint(lo.w), __float_as_uint(lo.z), 0x07060302u);
    r.u[2] = __builtin_amdgcn_perm(__float_as_uint(hi.y), __float_as_uint(hi.x), 0x07060302u);
    r.u[3] = __builtin_amdgcn_perm(__float_as_uint(hi.w), __float_as_uint(hi.z), 0x07060302u);
    return r.s;
  };

  // 18 K-steps, NO barriers. Issued = 16 + 2*min(s,10) (refills at s=0..9);
  // slot-s data = loads #2s+1,2s+2 -> wait N = min(14, 36-2(s+1)).
#pragma unroll
  for (int s = 0; s < 18; ++s) {
    const int slot = s & 7;
    if      (s <= 10) waitvm<14>();
    else if (s == 11) waitvm<12>();
    else if (s == 12) waitvm<10>();
    else if (s == 13) waitvm<8>();
    else if (s == 14) waitvm<6>();
    else if (s == 15) waitvm<4>();
    else if (s == 16) waitvm<2>();
    else              waitvm<0>();

    short8 b0 = pack(pf[slot][0], pf[slot][1]);

    const unsigned short* ab = ((s & 1) ? apO : apE) + (s >> 1) * 64;
    short8 a0 = *(const short8*)ab;                 // ds_read_b128
    short8 a1 = *(const short8*)(ab + 16 * PSTR);

    if (s + 8 < 18) ISSUE(slot, s + 8);             // refill same slot (consumed)

    acc0 = __builtin_amdgcn_mfma_f32_16x16x32_bf16(a0, b0, acc0, 0, 0, 0);
    acc1 = __builtin_amdgcn_mfma_f32_16x16x32_bf16(a1, b0, acc1, 0, 0, 0);
  }
#undef ISSUE

  // ---- epilogue: C/D layout col=lane&15, row=(lane>>4)*4+reg ----
  int o = wc * 16 + l15;
  float bv = bias[o * 1024 + hw];
  int m0 = l4 << 2;
#pragma unroll
  for (int r = 0; r < 4; ++r) {
    int b = (mh << 5) + m0 + r;
    out[((size_t)(b * 64 + o) << 10) + hw] = acc0[r] + bv;
    out[((size_t)((b + 16) * 64 + o) << 10) + hw] = acc1[r] + bv;
  }
}

extern "C" void kernel_launch(void* const* d_in, const int* in_sizes, int n_in,
                              void* d_out, int out_size, void* d_ws, size_t ws_size,
                              hipStream_t stream) {
  const float* x = (const float*)d_in[0];
  const float* wgt = (const float*)d_in[1];
  const float* bias = (const float*)d_in[2];
  float* out = (float*)d_out;
  unsigned short* xc = (unsigned short*)d_ws;  // 8 MB

  hipLaunchKernelGGL(xpose_k, dim3(1024), dim3(256), 0, stream, x, xc);
  hipLaunchKernelGGL(conv_k, dim3(2048), dim3(256), 0, stream, xc, wgt, bias, out);
}

// Round 7
// 55.239 us; speedup vs baseline: 1.1581x; 1.1581x over previous
//
#include <hip/hip_runtime.h>
#include <hip/hip_bf16.h>

// Conv2dLocal: B=64, C_IN=64, H=W=32, C_OUT=64, 3x3, pad 1, stride 1.
// out[b,o,h,w] = sum_{c,kh,kw} x[b,c,h+kh-1,w+kw-1] * wgt[h,w,o,c,kh,kw] + bias[o,h,w]
//
// xpose_k: x[b][c][y][xw] f32 -> xc[y][xw][b][c] bf16 (8 MB in d_ws)
// conv_k:  ONE block per hw (grid 1024) -> each weight panel read exactly ONCE.
//   Full batch M=64 im2col patch [64][576] bf16 in dynamic LDS (73.7 KB,
//   XOR-swizzled 16B units, conflict-free ds_write_b128 staging). Weights
//   PER-WAVE PRIVATE: pinned inline-asm global_load_dwordx4 ring (depth 8,
//   16 in flight, "=&v" early-clobber), consumed after s_waitcnt vmcnt(N) +
//   sched_barrier(0) (rule #18). NO barriers in K-loop. 4 waves x (64M x 16N).

typedef __attribute__((ext_vector_type(8))) short short8;
typedef __attribute__((ext_vector_type(4))) float f32x4;

#define PSTR 576  // patch row stride (bf16) = 72 16B-units; 72%8==0 -> swizzle exact

__device__ __forceinline__ void waitlgkm0() {
  asm volatile("s_waitcnt lgkmcnt(0)" ::: "memory");
}

// Wait until <=N vmem ops outstanding; sched_barrier(0) keeps register-only
// consumers (pack/MFMA) from being hoisted above the wait (guide rule #18).
template <int N>
__device__ __forceinline__ void waitvm() {
  asm volatile("s_waitcnt vmcnt(%0)" ::"i"(N) : "memory");
  __builtin_amdgcn_sched_barrier(0);
}

__global__ __launch_bounds__(256) void xpose_k(const float* __restrict__ x,
                                               unsigned short* __restrict__ xc) {
  __shared__ float tile[64][65];
  int bid = blockIdx.x;  // 64 row-tiles x 16 col-tiles over A[4096][1024]
  int rt = bid >> 4, ct = bid & 15;
  int r0 = rt << 6, c0 = ct << 6;
  int lane = threadIdx.x & 63, wv = threadIdx.x >> 6;
#pragma unroll
  for (int i = 0; i < 16; ++i) {
    int r = (i << 2) + wv;
    tile[r][lane] = x[(size_t)(r0 + r) * 1024 + c0 + lane];
  }
  __syncthreads();
#pragma unroll
  for (int i = 0; i < 16; ++i) {
    int oc = (i << 2) + wv;
    unsigned int u = __float_as_uint(tile[lane][oc]);
    unsigned int r = (u + 0x7FFFu + ((u >> 16) & 1u)) >> 16;  // RNE to bf16
    xc[(size_t)(c0 + oc) * 4096 + r0 + lane] = (unsigned short)r;
  }
}

__global__ __launch_bounds__(256, 2) void conv_k(const unsigned short* __restrict__ xc,
                                                 const float* __restrict__ wgt,
                                                 const float* __restrict__ bias,
                                                 float* __restrict__ out) {
  extern __shared__ unsigned short patch[];  // [64][PSTR] = 73,728 B dynamic

  int bid = blockIdx.x;
  int hw = ((bid & 7) << 7) | (bid >> 3);  // XCD gets 128 contiguous hw
  int h = hw >> 5, w = hw & 31;
  int t = threadIdx.x;

  // ---- stage im2col patch (all 64 batch rows): patch[b][k], k=c*9+tap ----
  {
    int c8 = t & 7;     // c octet
    int brow = t >> 3;  // 0..31
#pragma unroll
    for (int bh = 0; bh < 2; ++bh) {
      int row = brow + (bh << 5);
      uint4 v[9];
#pragma unroll
      for (int tap = 0; tap < 9; ++tap) {
        int y = h + tap / 3 - 1;
        int xw = w + tap % 3 - 1;
        bool valid = ((unsigned)y < 32u) && ((unsigned)xw < 32u);
        uint4 val = make_uint4(0u, 0u, 0u, 0u);
        if (valid)
          val = *(const uint4*)(xc + ((size_t)(y * 32 + xw) << 12) + row * 64 + c8 * 8);
        v[tap] = val;
      }
      unsigned short* dst = patch + row * PSTR;
      int r7b = row & 7;  // same for bh=0,1 (32 ≡ 0 mod 8)
      const unsigned int* vw = (const unsigned int*)v;
#pragma unroll
      for (int u = 0; u < 9; ++u) {
        unsigned int wd[4];
#pragma unroll
        for (int wi = 0; wi < 4; ++wi) {
          const int kl0 = 8 * u + 2 * wi, kl1 = kl0 + 1;
          const int tapA = kl0 % 9, jA = kl0 / 9;
          const int tapB = kl1 % 9, jB = kl1 / 9;
          const unsigned int selLo = (jA & 1) ? 0x0302u : 0x0100u;
          const unsigned int selHi = (jB & 1) ? 0x0706u : 0x0504u;
          wd[wi] = __builtin_amdgcn_perm(vw[tapB * 4 + (jB >> 1)],
                                         vw[tapA * 4 + (jA >> 1)],
                                         selLo | (selHi << 16));
        }
        int u_abs = 9 * c8 + u;
        int u_swz = (u_abs & ~7) | ((u_abs & 7) ^ r7b);
        *(uint4*)(dst + (u_swz << 3)) = make_uint4(wd[0], wd[1], wd[2], wd[3]);
      }
    }
  }

  // ---- per-wave private weight stream: pinned asm loads, depth-8 ring ----
  int wc = t >> 6, lane = t & 63;
  int l15 = lane & 15, l4 = lane >> 4;
  const float* wb = wgt + (size_t)hw * 36864;                 // [64 o][576 k] f32
  const float* wp = wb + (size_t)(wc * 16 + l15) * 576 + l4 * 8;

  float4 pf[8][2];  // all indices static after unroll -> registers

  // EARLY-CLOBBER outputs: async dest regs must not alias the address pair.
#define ISSUE(slot, step)                                              \
  do {                                                                 \
    const float* _a = wp + (step) * 32;                                \
    asm volatile("global_load_dwordx4 %0, %2, off\n\t"                 \
                 "global_load_dwordx4 %1, %2, off offset:16"           \
                 : "=&v"(pf[slot][0]), "=&v"(pf[slot][1])              \
                 : "v"(_a)                                             \
                 : "memory");                                          \
  } while (0)

  // prologue: fill all 8 slots (staging xc loads fully drained — in-order
  // vmcnt returns, last ds_write waited on the last staging load)
  ISSUE(0, 0); ISSUE(1, 1); ISSUE(2, 2); ISSUE(3, 3);
  ISSUE(4, 4); ISSUE(5, 5); ISSUE(6, 6); ISSUE(7, 7);

  waitlgkm0();                          // own patch ds_writes complete
  __builtin_amdgcn_sched_barrier(0);
  __builtin_amdgcn_s_barrier();         // patch visible; 16 weight loads in flight

  // A-read bases (swizzled): step s unit low3 = (4*(s&1)+l4)^(l15&7)
  int l7 = l15 & 7;
  const unsigned short* apE = patch + l15 * PSTR + ((l4 ^ l7) << 3);
  const unsigned short* apO = patch + l15 * PSTR + (((4 + l4) ^ l7) << 3);

  f32x4 acc0 = {0.f, 0.f, 0.f, 0.f};
  f32x4 acc1 = acc0, acc2 = acc0, acc3 = acc0;

  union S8U { short8 s; unsigned int u[4]; };
  auto pack = [](const float4& lo, const float4& hi) -> short8 {
    S8U r;  // truncate f32->bf16 via v_perm
    r.u[0] = __builtin_amdgcn_perm(__float_as_uint(lo.y), __float_as_uint(lo.x), 0x07060302u);
    r.u[1] = __builtin_amdgcn_perm(__float_as_uint(lo.w), __float_as_uint(lo.z), 0x07060302u);
    r.u[2] = __builtin_amdgcn_perm(__float_as_uint(hi.y), __float_as_uint(hi.x), 0x07060302u);
    r.u[3] = __builtin_amdgcn_perm(__float_as_uint(hi.w), __float_as_uint(hi.z), 0x07060302u);
    return r.s;
  };

  // 18 K-steps, NO barriers. Issued = 16 + 2*min(s,10) (refills at s=0..9);
  // slot-s data = loads #2s+1,2s+2 -> wait N = min(14, 36-2(s+1)).
#pragma unroll
  for (int s = 0; s < 18; ++s) {
    const int slot = s & 7;
    if      (s <= 10) waitvm<14>();
    else if (s == 11) waitvm<12>();
    else if (s == 12) waitvm<10>();
    else if (s == 13) waitvm<8>();
    else if (s == 14) waitvm<6>();
    else if (s == 15) waitvm<4>();
    else if (s == 16) waitvm<2>();
    else              waitvm<0>();

    short8 b0 = pack(pf[slot][0], pf[slot][1]);

    const unsigned short* ab = ((s & 1) ? apO : apE) + (s >> 1) * 64;
    short8 a0 = *(const short8*)ab;                 // ds_read_b128 x4
    short8 a1 = *(const short8*)(ab + 16 * PSTR);
    short8 a2 = *(const short8*)(ab + 32 * PSTR);
    short8 a3 = *(const short8*)(ab + 48 * PSTR);

    if (s + 8 < 18) ISSUE(slot, s + 8);             // refill same slot (consumed)

    acc0 = __builtin_amdgcn_mfma_f32_16x16x32_bf16(a0, b0, acc0, 0, 0, 0);
    acc1 = __builtin_amdgcn_mfma_f32_16x16x32_bf16(a1, b0, acc1, 0, 0, 0);
    acc2 = __builtin_amdgcn_mfma_f32_16x16x32_bf16(a2, b0, acc2, 0, 0, 0);
    acc3 = __builtin_amdgcn_mfma_f32_16x16x32_bf16(a3, b0, acc3, 0, 0, 0);
  }
#undef ISSUE

  // ---- epilogue: C/D layout col=lane&15, row=(lane>>4)*4+reg ----
  int o = wc * 16 + l15;
  float bv = bias[o * 1024 + hw];
  int m0 = l4 << 2;
#pragma unroll
  for (int r = 0; r < 4; ++r) {
    int b = m0 + r;
    out[((size_t)((b)*64 + o) << 10) + hw]        = acc0[r] + bv;
    out[((size_t)((b + 16) * 64 + o) << 10) + hw] = acc1[r] + bv;
    out[((size_t)((b + 32) * 64 + o) << 10) + hw] = acc2[r] + bv;
    out[((size_t)((b + 48) * 64 + o) << 10) + hw] = acc3[r] + bv;
  }
}

extern "C" void kernel_launch(void* const* d_in, const int* in_sizes, int n_in,
                              void* d_out, int out_size, void* d_ws, size_t ws_size,
                              hipStream_t stream) {
  const float* x = (const float*)d_in[0];
  const float* wgt = (const float*)d_in[1];
  const float* bias = (const float*)d_in[2];
  float* out = (float*)d_out;
  unsigned short* xc = (unsigned short*)d_ws;  // 8 MB

  const int conv_lds = 64 * PSTR * 2;  // 73,728 B dynamic LDS
  (void)hipFuncSetAttribute((const void*)conv_k,
                            hipFuncAttributeMaxDynamicSharedMemorySize, conv_lds);

  hipLaunchKernelGGL(xpose_k, dim3(1024), dim3(256), 0, stream, x, xc);
  hipLaunchKernelGGL(conv_k, dim3(1024), dim3(256), conv_lds, stream, xc, wgt, bias, out);
}